// Round 1
// baseline (2776.738 us; speedup 1.0000x reference)
//
#include <hip/hip_runtime.h>
#include <math.h>

// Sizes (fixed by the problem)
#define VOCAB 50000
#define EDIM  200
#define HDIM  256
#define G3    768      // 3*H
#define NSEQ1 4096     // B*R*S word sequences
#define T1    32       // W
#define NSEQ2 256      // B*R sentence sequences
#define T2    16       // S
#define NSEQ3 16       // B review sequences
#define T3    16       // R

__device__ __forceinline__ float sigmoid_f(float x) {
    return 1.0f / (1.0f + __expf(-x));
}
__device__ __forceinline__ float tanh_f(float x) {
    // 1 - 2/(e^{2x}+1); saturates correctly at +-1
    return 1.0f - 2.0f / (__expf(2.0f * x) + 1.0f);
}

// ---------------------------------------------------------------------------
// C[M,768] = A[M,K] @ W[768,K]^T + bias[768]
// 64x64 tile, 256 threads, 4x4 micro-tile, K in chunks of 8 (200 and 256 both
// divide by 8). fp32 vector GEMM (no fp32 MFMA exists on CDNA4).
// ---------------------------------------------------------------------------
__global__ __launch_bounds__(256) void gemm_bias(
    const float* __restrict__ A, const float* __restrict__ W,
    const float* __restrict__ bias, float* __restrict__ C,
    int M, int K) {
    __shared__ float As[8][64];
    __shared__ float Ws[8][64];
    const int tid = threadIdx.x;
    const int m0 = blockIdx.x * 64;
    const int n0 = blockIdx.y * 64;
    const int tx = tid & 15, ty = tid >> 4;
    const int lm = tid & 63;          // row within tile for loads
    const int lk = (tid >> 6) * 2;    // k pair 0,2,4,6

    float acc[4][4] = {};

    for (int kb = 0; kb < K; kb += 8) {
        const int am = m0 + lm;
        float2 av = make_float2(0.f, 0.f);
        if (am < M) av = *(const float2*)&A[(size_t)am * K + kb + lk];
        As[lk][lm] = av.x; As[lk + 1][lm] = av.y;
        float2 wv = *(const float2*)&W[(size_t)(n0 + lm) * K + kb + lk];
        Ws[lk][lm] = wv.x; Ws[lk + 1][lm] = wv.y;
        __syncthreads();
#pragma unroll
        for (int kk = 0; kk < 8; kk++) {
            const float4 a4 = *(const float4*)&As[kk][ty * 4];
            const float4 b4 = *(const float4*)&Ws[kk][tx * 4];
            const float a[4] = {a4.x, a4.y, a4.z, a4.w};
            const float b[4] = {b4.x, b4.y, b4.z, b4.w};
#pragma unroll
            for (int i = 0; i < 4; i++)
#pragma unroll
                for (int j = 0; j < 4; j++) acc[i][j] += a[i] * b[j];
        }
        __syncthreads();
    }

    const float4 bb = *(const float4*)&bias[n0 + tx * 4];
#pragma unroll
    for (int i = 0; i < 4; i++) {
        const int row = m0 + ty * 4 + i;
        if (row < M) {
            float4 o;
            o.x = acc[i][0] + bb.x; o.y = acc[i][1] + bb.y;
            o.z = acc[i][2] + bb.z; o.w = acc[i][3] + bb.w;
            *(float4*)&C[(size_t)row * G3 + n0 + tx * 4] = o;
        }
    }
}

// ---------------------------------------------------------------------------
// Word-level GRU: each block owns TM sequences, loops over T steps.
// Thread j (0..255) computes gates (j, 256+j, 512+j) for all TM rows.
// gx comes from gathered rows of P (= emb@Wih^T + bih, precomputed).
// h tile in LDS; reads of h are same-address broadcasts (conflict-free).
// ---------------------------------------------------------------------------
template <int TM>
__global__ __launch_bounds__(256) void gru_word(
    const int* __restrict__ idx,     // [NSEQ1, T1]
    const float* __restrict__ P,     // [VOCAB, 768]
    const float* __restrict__ Whh,   // [768, 256]
    const float* __restrict__ bhh,   // [768]
    float* __restrict__ hout,        // [NSEQ1, 256]
    int T) {
    __shared__ float hs[TM][HDIM];
    __shared__ int toks[TM];
    const int tid = threadIdx.x;
    const int n0 = blockIdx.x * TM;

#pragma unroll
    for (int r = 0; r < TM; r++) hs[r][tid] = 0.f;
    if (tid < TM) {
        int tk = idx[(size_t)(n0 + tid) * T];
        toks[tid] = min(max(tk, 0), VOCAB - 1);
    }
    const float bhr = bhh[tid];
    const float bhz = bhh[256 + tid];
    const float bhn = bhh[512 + tid];
    const float* Wr = Whh + (size_t)tid * HDIM;
    const float* Wz = Whh + (size_t)(256 + tid) * HDIM;
    const float* Wn = Whh + (size_t)(512 + tid) * HDIM;

    float hnew[TM];
    __syncthreads();

    for (int t = 0; t < T; t++) {
        float ar[TM] = {}, az[TM] = {}, an[TM] = {};
#pragma unroll 2
        for (int k = 0; k < HDIM; k += 4) {
            const float4 wr = *(const float4*)&Wr[k];
            const float4 wz = *(const float4*)&Wz[k];
            const float4 wn = *(const float4*)&Wn[k];
#pragma unroll
            for (int r = 0; r < TM; r++) {
                const float4 hv = *(const float4*)&hs[r][k];  // broadcast
                ar[r] += hv.x * wr.x; ar[r] += hv.y * wr.y;
                ar[r] += hv.z * wr.z; ar[r] += hv.w * wr.w;
                az[r] += hv.x * wz.x; az[r] += hv.y * wz.y;
                az[r] += hv.z * wz.z; az[r] += hv.w * wz.w;
                an[r] += hv.x * wn.x; an[r] += hv.y * wn.y;
                an[r] += hv.z * wn.z; an[r] += hv.w * wn.w;
            }
        }
#pragma unroll
        for (int r = 0; r < TM; r++) {
            const float* gx = P + (size_t)toks[r] * G3;
            const float xr = gx[tid];
            const float xz = gx[256 + tid];
            const float xn = gx[512 + tid];
            const float rg = sigmoid_f(xr + ar[r] + bhr);
            const float zg = sigmoid_f(xz + az[r] + bhz);
            const float ng = tanh_f(xn + rg * (an[r] + bhn));
            hnew[r] = (1.f - zg) * ng + zg * hs[r][tid];
        }
        __syncthreads();
#pragma unroll
        for (int r = 0; r < TM; r++) hs[r][tid] = hnew[r];
        if (tid < TM && t + 1 < T) {
            int tk = idx[(size_t)(n0 + tid) * T + t + 1];
            toks[tid] = min(max(tk, 0), VOCAB - 1);
        }
        __syncthreads();
    }
#pragma unroll
    for (int r = 0; r < TM; r++)
        hout[(size_t)(n0 + r) * HDIM + tid] = hnew[r];
}

// ---------------------------------------------------------------------------
// Sequence GRU with precomputed input gates gx[(n*T+t), 768].
// ---------------------------------------------------------------------------
template <int TM>
__global__ __launch_bounds__(256) void gru_seq(
    const float* __restrict__ gx,    // [Nseq*T, 768]
    const float* __restrict__ Whh,
    const float* __restrict__ bhh,
    float* __restrict__ hout,        // [Nseq, 256]
    int T) {
    __shared__ float hs[TM][HDIM];
    const int tid = threadIdx.x;
    const int n0 = blockIdx.x * TM;

#pragma unroll
    for (int r = 0; r < TM; r++) hs[r][tid] = 0.f;
    const float bhr = bhh[tid];
    const float bhz = bhh[256 + tid];
    const float bhn = bhh[512 + tid];
    const float* Wr = Whh + (size_t)tid * HDIM;
    const float* Wz = Whh + (size_t)(256 + tid) * HDIM;
    const float* Wn = Whh + (size_t)(512 + tid) * HDIM;

    float hnew[TM];
    __syncthreads();

    for (int t = 0; t < T; t++) {
        float ar[TM] = {}, az[TM] = {}, an[TM] = {};
#pragma unroll 2
        for (int k = 0; k < HDIM; k += 4) {
            const float4 wr = *(const float4*)&Wr[k];
            const float4 wz = *(const float4*)&Wz[k];
            const float4 wn = *(const float4*)&Wn[k];
#pragma unroll
            for (int r = 0; r < TM; r++) {
                const float4 hv = *(const float4*)&hs[r][k];
                ar[r] += hv.x * wr.x; ar[r] += hv.y * wr.y;
                ar[r] += hv.z * wr.z; ar[r] += hv.w * wr.w;
                az[r] += hv.x * wz.x; az[r] += hv.y * wz.y;
                az[r] += hv.z * wz.z; az[r] += hv.w * wz.w;
                an[r] += hv.x * wn.x; an[r] += hv.y * wn.y;
                an[r] += hv.z * wn.z; an[r] += hv.w * wn.w;
            }
        }
#pragma unroll
        for (int r = 0; r < TM; r++) {
            const float* g = gx + ((size_t)(n0 + r) * T + t) * G3;
            const float xr = g[tid];
            const float xz = g[256 + tid];
            const float xn = g[512 + tid];
            const float rg = sigmoid_f(xr + ar[r] + bhr);
            const float zg = sigmoid_f(xz + az[r] + bhz);
            const float ng = tanh_f(xn + rg * (an[r] + bhn));
            hnew[r] = (1.f - zg) * ng + zg * hs[r][tid];
        }
        __syncthreads();
#pragma unroll
        for (int r = 0; r < TM; r++) hs[r][tid] = hnew[r];
        __syncthreads();
    }
#pragma unroll
    for (int r = 0; r < TM; r++)
        hout[(size_t)(n0 + r) * HDIM + tid] = hnew[r];
}

// ---------------------------------------------------------------------------
// MLP head: out[row] = selu(h[row]@W1^T + b1) @ W2^T + b2
// one block (128 threads) per row.
// ---------------------------------------------------------------------------
__global__ __launch_bounds__(128) void mlp_head(
    const float* __restrict__ hin,   // [Nrow, 256]
    const float* __restrict__ W1,    // [128, 256]
    const float* __restrict__ b1,    // [128]
    const float* __restrict__ W2,    // [1, 128]
    const float* __restrict__ b2,    // [1]
    float* __restrict__ out) {       // [Nrow]
    const int row = blockIdx.x;
    const int g = threadIdx.x;       // 0..127
    const float* h = hin + (size_t)row * HDIM;
    const float* w = W1 + (size_t)g * HDIM;
    float acc = 0.f;
#pragma unroll 4
    for (int k = 0; k < HDIM; k += 4) {
        const float4 hv = *(const float4*)&h[k];
        const float4 wv = *(const float4*)&w[k];
        acc += hv.x * wv.x; acc += hv.y * wv.y;
        acc += hv.z * wv.z; acc += hv.w * wv.w;
    }
    acc += b1[g];
    const float alpha = 1.6732632423543772f;
    const float scale = 1.0507009873554805f;
    const float s = scale * (acc > 0.f ? acc : alpha * expm1f(acc));
    float v = s * W2[g];

    __shared__ float red[128];
    red[g] = v;
    __syncthreads();
    if (g < 64) {
        float x = red[g] + red[g + 64];
#pragma unroll
        for (int off = 32; off; off >>= 1) x += __shfl_down(x, off);
        if (g == 0) out[row] = x + b2[0];
    }
}

// ---------------------------------------------------------------------------
extern "C" void kernel_launch(void* const* d_in, const int* in_sizes, int n_in,
                              void* d_out, int out_size, void* d_ws, size_t ws_size,
                              hipStream_t stream) {
    const int*   idx    = (const int*)d_in[0];
    const float* emb    = (const float*)d_in[1];
    const float* w_Wih  = (const float*)d_in[2];
    const float* w_Whh  = (const float*)d_in[3];
    const float* w_bih  = (const float*)d_in[4];
    const float* w_bhh  = (const float*)d_in[5];
    const float* s_Wih  = (const float*)d_in[6];
    const float* s_Whh  = (const float*)d_in[7];
    const float* s_bih  = (const float*)d_in[8];
    const float* s_bhh  = (const float*)d_in[9];
    const float* r_Wih  = (const float*)d_in[10];
    const float* r_Whh  = (const float*)d_in[11];
    const float* r_bih  = (const float*)d_in[12];
    const float* r_bhh  = (const float*)d_in[13];
    const float* rfc_W1 = (const float*)d_in[14];
    const float* rfc_b1 = (const float*)d_in[15];
    const float* rfc_W2 = (const float*)d_in[16];
    const float* rfc_b2 = (const float*)d_in[17];
    const float* pfc_W1 = (const float*)d_in[18];
    const float* pfc_b1 = (const float*)d_in[19];
    const float* pfc_W2 = (const float*)d_in[20];
    const float* pfc_b2 = (const float*)d_in[21];

    float* out = (float*)d_out;      // [0..15] b_stars, [16..271] r_stars
    float* ws  = (float*)d_ws;

    // Workspace layout (floats)
    float* P      = ws;                                    // 50000*768
    float* sent_h = P      + (size_t)VOCAB * G3;           // 4096*256
    float* gx2    = sent_h + (size_t)NSEQ1 * HDIM;         // 4096*768
    float* rev_h  = gx2    + (size_t)NSEQ1 * G3;           // 256*256
    float* gx3    = rev_h  + (size_t)NSEQ2 * HDIM;         // 256*768
    float* biz_h  = gx3    + (size_t)NSEQ2 * G3;           // 16*256

    // 1) Project whole embedding table: P = emb @ w_Wih^T + w_bih
    gemm_bias<<<dim3((VOCAB + 63) / 64, G3 / 64), 256, 0, stream>>>(
        emb, w_Wih, w_bih, P, VOCAB, EDIM);

    // 2) Word-level GRU over 4096 sequences of 32 steps
    gru_word<16><<<NSEQ1 / 16, 256, 0, stream>>>(
        idx, P, w_Whh, w_bhh, sent_h, T1);

    // 3) Sentence GRU input gates: gx2 = sent_h @ s_Wih^T + s_bih
    gemm_bias<<<dim3(NSEQ1 / 64, G3 / 64), 256, 0, stream>>>(
        sent_h, s_Wih, s_bih, gx2, NSEQ1, HDIM);

    // 4) Sentence-level GRU: 256 sequences of 16 steps -> rev_h
    gru_seq<4><<<NSEQ2 / 4, 256, 0, stream>>>(
        gx2, s_Whh, s_bhh, rev_h, T2);

    // 5) r_stars = mlp(rev_h) -> out[16..271]
    mlp_head<<<NSEQ2, 128, 0, stream>>>(
        rev_h, rfc_W1, rfc_b1, rfc_W2, rfc_b2, out + 16);

    // 6) Review GRU input gates: gx3 = rev_h @ r_Wih^T + r_bih
    gemm_bias<<<dim3(NSEQ2 / 64, G3 / 64), 256, 0, stream>>>(
        rev_h, r_Wih, r_bih, gx3, NSEQ2, HDIM);

    // 7) Review-level GRU: 16 sequences of 16 steps -> biz_h
    gru_seq<1><<<NSEQ3, 256, 0, stream>>>(
        gx3, r_Whh, r_bhh, biz_h, T3);

    // 8) b_stars = mlp(biz_h) -> out[0..15]
    mlp_head<<<NSEQ3, 128, 0, stream>>>(
        biz_h, pfc_W1, pfc_b1, pfc_W2, pfc_b2, out);
}

// Round 2
// 2574.530 us; speedup vs baseline: 1.0785x; 1.0785x over previous
//
#include <hip/hip_runtime.h>
#include <math.h>

// Sizes (fixed by the problem)
#define VOCAB 50000
#define EDIM  200
#define HDIM  256
#define G3    768      // 3*H
#define NSEQ1 4096     // B*R*S word sequences
#define T1    32       // W
#define NSEQ2 256      // B*R sentence sequences
#define T2    16       // S
#define NSEQ3 16       // B review sequences
#define T3    16       // R

__device__ __forceinline__ float sigmoid_f(float x) {
    return 1.0f / (1.0f + __expf(-x));
}
__device__ __forceinline__ float tanh_f(float x) {
    return 1.0f - 2.0f / (__expf(2.0f * x) + 1.0f);
}

// ---------------------------------------------------------------------------
// C[M,768] = A[M,K] @ W[768,K]^T + bias[768]
// Tile 128(M) x 64(N), 256 threads, 8x4 micro-tile, K chunks of 8.
// ---------------------------------------------------------------------------
__global__ __launch_bounds__(256) void gemm_bias(
    const float* __restrict__ A, const float* __restrict__ W,
    const float* __restrict__ bias, float* __restrict__ C,
    int M, int K) {
    __shared__ float As[8][128];
    __shared__ float Ws[8][64];
    const int tid = threadIdx.x;
    const int m0 = blockIdx.x * 128;
    const int n0 = blockIdx.y * 64;
    const int tx = tid & 15, ty = tid >> 4;   // 16x16 thread grid

    // staging indices
    const int alm = tid >> 1;                  // 0..127 (A row in tile)
    const int alk = (tid & 1) * 4;             // 0 or 4
    const int wlb = tid >> 1;                  // 0..127, use <64
    const int wlk = (tid & 1) * 4;

    float acc[8][4] = {};

    for (int kb = 0; kb < K; kb += 8) {
        // stage A tile (128 rows x 8 k)
        {
            const int am = m0 + alm;
            float4 av = make_float4(0.f, 0.f, 0.f, 0.f);
            if (am < M) av = *(const float4*)&A[(size_t)am * K + kb + alk];
            As[alk + 0][alm] = av.x; As[alk + 1][alm] = av.y;
            As[alk + 2][alm] = av.z; As[alk + 3][alm] = av.w;
        }
        // stage W tile (64 rows x 8 k)
        if (wlb < 64) {
            float4 wv = *(const float4*)&W[(size_t)(n0 + wlb) * K + kb + wlk];
            Ws[wlk + 0][wlb] = wv.x; Ws[wlk + 1][wlb] = wv.y;
            Ws[wlk + 2][wlb] = wv.z; Ws[wlk + 3][wlb] = wv.w;
        }
        __syncthreads();
#pragma unroll
        for (int kk = 0; kk < 8; kk++) {
            const float4 a0 = *(const float4*)&As[kk][ty * 8];
            const float4 a1 = *(const float4*)&As[kk][ty * 8 + 4];
            const float4 b4 = *(const float4*)&Ws[kk][tx * 4];
            const float a[8] = {a0.x, a0.y, a0.z, a0.w, a1.x, a1.y, a1.z, a1.w};
            const float b[4] = {b4.x, b4.y, b4.z, b4.w};
#pragma unroll
            for (int i = 0; i < 8; i++)
#pragma unroll
                for (int j = 0; j < 4; j++) acc[i][j] += a[i] * b[j];
        }
        __syncthreads();
    }

    const float4 bb = *(const float4*)&bias[n0 + tx * 4];
#pragma unroll
    for (int i = 0; i < 8; i++) {
        const int row = m0 + ty * 8 + i;
        if (row < M) {
            float4 o;
            o.x = acc[i][0] + bb.x; o.y = acc[i][1] + bb.y;
            o.z = acc[i][2] + bb.z; o.w = acc[i][3] + bb.w;
            *(float4*)&C[(size_t)row * G3 + n0 + tx * 4] = o;
        }
    }
}

// ---------------------------------------------------------------------------
// Word-level GRU, two-phase structure, 1024 threads.
//  Phase A: threads 0..767 each own one gate row g of Whh and compute
//           acc[r] = h[r] . Whh[g] for all TM sequences (LDS broadcast reads);
//           threads 768..1023 gather gx rows from P into LDS (hides L3 lat).
//  Phase B: all 1024 threads apply gate nonlinearities + h update.
// ---------------------------------------------------------------------------
template <int TM>
__global__ __launch_bounds__(1024) void gru_word(
    const int* __restrict__ idx,     // [NSEQ1, T]
    const float* __restrict__ P,     // [VOCAB, 768] = emb@Wih^T + bih
    const float* __restrict__ Whh,   // [768, 256]
    const float* __restrict__ bhh,   // [768]
    float* __restrict__ hout,        // [NSEQ1, 256]
    int T) {
    __shared__ float hs[TM][HDIM];   // 16 KB
    __shared__ float pre[TM][G3];    // 48 KB
    __shared__ float gxs[TM][G3];    // 48 KB
    __shared__ int toks[TM];
    const int tid = threadIdx.x;
    const int n0 = blockIdx.x * TM;

    // init
    for (int w = tid; w < TM * HDIM; w += 1024) ((float*)hs)[w] = 0.f;
    if (tid < TM) {
        int tk = idx[(size_t)(n0 + tid) * T];
        toks[tid] = min(max(tk, 0), VOCAB - 1);
    }

    const int g = tid;                       // gate row for dot threads
    const float* wrow = Whh + (size_t)g * HDIM;
    float bh = 0.f;
    if (g < G3) bh = bhh[g];

    __syncthreads();

    for (int t = 0; t < T; t++) {
        // ---------------- Phase A ----------------
        if (g < G3) {
            float acc[TM];
#pragma unroll
            for (int r = 0; r < TM; r++) acc[r] = 0.f;
#pragma unroll 2
            for (int k = 0; k < HDIM; k += 8) {
                const float4 w0 = *(const float4*)&wrow[k];
                const float4 w1 = *(const float4*)&wrow[k + 4];
#pragma unroll
                for (int r = 0; r < TM; r++) {
                    const float4 h0 = *(const float4*)&hs[r][k];      // broadcast
                    const float4 h1 = *(const float4*)&hs[r][k + 4];  // broadcast
                    acc[r] += h0.x * w0.x; acc[r] += h0.y * w0.y;
                    acc[r] += h0.z * w0.z; acc[r] += h0.w * w0.w;
                    acc[r] += h1.x * w1.x; acc[r] += h1.y * w1.y;
                    acc[r] += h1.z * w1.z; acc[r] += h1.w * w1.w;
                }
            }
#pragma unroll
            for (int r = 0; r < TM; r++) pre[r][g] = acc[r] + bh;
        } else {
            const int lane = tid - G3;       // 0..255
#pragma unroll
            for (int r = 0; r < TM; r++) {
                const float* src = P + (size_t)toks[r] * G3;
                for (int c = lane; c < G3; c += 256) gxs[r][c] = src[c];
            }
        }
        __syncthreads();

        // ---------------- Phase B ----------------
        for (int w = tid; w < TM * HDIM; w += 1024) {
            const int r = w >> 8, j = w & 255;
            const float xr = gxs[r][j];
            const float xz = gxs[r][256 + j];
            const float xn = gxs[r][512 + j];
            const float ar = pre[r][j];
            const float az = pre[r][256 + j];
            const float an = pre[r][512 + j];
            const float rg = sigmoid_f(xr + ar);
            const float zg = sigmoid_f(xz + az);
            const float ng = tanh_f(xn + rg * an);
            hs[r][j] = (1.f - zg) * ng + zg * hs[r][j];
        }
        if (tid < TM && t + 1 < T) {
            int tk = idx[(size_t)(n0 + tid) * T + t + 1];
            toks[tid] = min(max(tk, 0), VOCAB - 1);
        }
        __syncthreads();
    }

    for (int w = tid; w < TM * HDIM; w += 1024)
        hout[(size_t)(n0 + (w >> 8)) * HDIM + (w & 255)] = hs[w >> 8][w & 255];
}

// ---------------------------------------------------------------------------
// Sequence GRU with precomputed input gates gx[(n*T+t), 768].
// Two-phase, 768 threads, TM sequences per block.
// ---------------------------------------------------------------------------
template <int TM>
__global__ __launch_bounds__(768) void gru_seq(
    const float* __restrict__ gx,    // [Nseq*T, 768]
    const float* __restrict__ Whh,
    const float* __restrict__ bhh,
    float* __restrict__ hout,        // [Nseq, 256]
    int T) {
    __shared__ float hs[TM][HDIM];
    __shared__ float pre[TM][G3];
    const int tid = threadIdx.x;
    const int n0 = blockIdx.x * TM;

    for (int w = tid; w < TM * HDIM; w += 768) ((float*)hs)[w] = 0.f;

    const int g = tid;
    const float* wrow = Whh + (size_t)g * HDIM;
    const float bh = bhh[g];

    __syncthreads();

    for (int t = 0; t < T; t++) {
        // Phase A: dot products
        {
            float acc[TM];
#pragma unroll
            for (int r = 0; r < TM; r++) acc[r] = 0.f;
#pragma unroll 4
            for (int k = 0; k < HDIM; k += 8) {
                const float4 w0 = *(const float4*)&wrow[k];
                const float4 w1 = *(const float4*)&wrow[k + 4];
#pragma unroll
                for (int r = 0; r < TM; r++) {
                    const float4 h0 = *(const float4*)&hs[r][k];
                    const float4 h1 = *(const float4*)&hs[r][k + 4];
                    acc[r] += h0.x * w0.x; acc[r] += h0.y * w0.y;
                    acc[r] += h0.z * w0.z; acc[r] += h0.w * w0.w;
                    acc[r] += h1.x * w1.x; acc[r] += h1.y * w1.y;
                    acc[r] += h1.z * w1.z; acc[r] += h1.w * w1.w;
                }
            }
#pragma unroll
            for (int r = 0; r < TM; r++) pre[r][g] = acc[r] + bh;
        }
        __syncthreads();

        // Phase B
        if (tid < TM * HDIM) {
            const int r = tid >> 8, j = tid & 255;
            const float* gp = gx + ((size_t)(n0 + r) * T + t) * G3;
            const float xr = gp[j];
            const float xz = gp[256 + j];
            const float xn = gp[512 + j];
            const float ar = pre[r][j];
            const float az = pre[r][256 + j];
            const float an = pre[r][512 + j];
            const float rg = sigmoid_f(xr + ar);
            const float zg = sigmoid_f(xz + az);
            const float ng = tanh_f(xn + rg * an);
            hs[r][j] = (1.f - zg) * ng + zg * hs[r][j];
        }
        __syncthreads();
    }

    for (int w = tid; w < TM * HDIM; w += 768)
        hout[(size_t)(n0 + (w >> 8)) * HDIM + (w & 255)] = hs[w >> 8][w & 255];
}

// ---------------------------------------------------------------------------
// MLP head: out[row] = selu(h[row]@W1^T + b1) @ W2^T + b2
// ---------------------------------------------------------------------------
__global__ __launch_bounds__(128) void mlp_head(
    const float* __restrict__ hin,   // [Nrow, 256]
    const float* __restrict__ W1,    // [128, 256]
    const float* __restrict__ b1,    // [128]
    const float* __restrict__ W2,    // [1, 128]
    const float* __restrict__ b2,    // [1]
    float* __restrict__ out) {       // [Nrow]
    const int row = blockIdx.x;
    const int gg = threadIdx.x;      // 0..127
    const float* h = hin + (size_t)row * HDIM;
    const float* w = W1 + (size_t)gg * HDIM;
    float acc = 0.f;
#pragma unroll 4
    for (int k = 0; k < HDIM; k += 4) {
        const float4 hv = *(const float4*)&h[k];
        const float4 wv = *(const float4*)&w[k];
        acc += hv.x * wv.x; acc += hv.y * wv.y;
        acc += hv.z * wv.z; acc += hv.w * wv.w;
    }
    acc += b1[gg];
    const float alpha = 1.6732632423543772f;
    const float scale = 1.0507009873554805f;
    const float s = scale * (acc > 0.f ? acc : alpha * expm1f(acc));
    float v = s * W2[gg];

    __shared__ float red[128];
    red[gg] = v;
    __syncthreads();
    if (gg < 64) {
        float x = red[gg] + red[gg + 64];
#pragma unroll
        for (int off = 32; off; off >>= 1) x += __shfl_down(x, off);
        if (gg == 0) out[row] = x + b2[0];
    }
}

// ---------------------------------------------------------------------------
extern "C" void kernel_launch(void* const* d_in, const int* in_sizes, int n_in,
                              void* d_out, int out_size, void* d_ws, size_t ws_size,
                              hipStream_t stream) {
    const int*   idx    = (const int*)d_in[0];
    const float* emb    = (const float*)d_in[1];
    const float* w_Wih  = (const float*)d_in[2];
    const float* w_Whh  = (const float*)d_in[3];
    const float* w_bih  = (const float*)d_in[4];
    const float* w_bhh  = (const float*)d_in[5];
    const float* s_Wih  = (const float*)d_in[6];
    const float* s_Whh  = (const float*)d_in[7];
    const float* s_bih  = (const float*)d_in[8];
    const float* s_bhh  = (const float*)d_in[9];
    const float* r_Wih  = (const float*)d_in[10];
    const float* r_Whh  = (const float*)d_in[11];
    const float* r_bih  = (const float*)d_in[12];
    const float* r_bhh  = (const float*)d_in[13];
    const float* rfc_W1 = (const float*)d_in[14];
    const float* rfc_b1 = (const float*)d_in[15];
    const float* rfc_W2 = (const float*)d_in[16];
    const float* rfc_b2 = (const float*)d_in[17];
    const float* pfc_W1 = (const float*)d_in[18];
    const float* pfc_b1 = (const float*)d_in[19];
    const float* pfc_W2 = (const float*)d_in[20];
    const float* pfc_b2 = (const float*)d_in[21];

    float* out = (float*)d_out;      // [0..15] b_stars, [16..271] r_stars
    float* ws  = (float*)d_ws;

    // Workspace layout (floats)
    float* P      = ws;                                    // 50000*768
    float* sent_h = P      + (size_t)VOCAB * G3;           // 4096*256
    float* gx2    = sent_h + (size_t)NSEQ1 * HDIM;         // 4096*768
    float* rev_h  = gx2    + (size_t)NSEQ1 * G3;           // 256*256
    float* gx3    = rev_h  + (size_t)NSEQ2 * HDIM;         // 256*768
    float* biz_h  = gx3    + (size_t)NSEQ2 * G3;           // 16*256

    // 1) P = emb @ w_Wih^T + w_bih   [50000 x 768], K=200
    gemm_bias<<<dim3((VOCAB + 127) / 128, G3 / 64), 256, 0, stream>>>(
        emb, w_Wih, w_bih, P, VOCAB, EDIM);

    // 2) Word-level GRU: 4096 sequences x 32 steps
    gru_word<16><<<NSEQ1 / 16, 1024, 0, stream>>>(
        idx, P, w_Whh, w_bhh, sent_h, T1);

    // 3) gx2 = sent_h @ s_Wih^T + s_bih   [4096 x 768], K=256
    gemm_bias<<<dim3(NSEQ1 / 128, G3 / 64), 256, 0, stream>>>(
        sent_h, s_Wih, s_bih, gx2, NSEQ1, HDIM);

    // 4) Sentence-level GRU: 256 sequences x 16 steps
    gru_seq<2><<<NSEQ2 / 2, 768, 0, stream>>>(
        gx2, s_Whh, s_bhh, rev_h, T2);

    // 5) r_stars -> out[16..271]
    mlp_head<<<NSEQ2, 128, 0, stream>>>(
        rev_h, rfc_W1, rfc_b1, rfc_W2, rfc_b2, out + 16);

    // 6) gx3 = rev_h @ r_Wih^T + r_bih   [256 x 768], K=256
    gemm_bias<<<dim3((NSEQ2 + 127) / 128, G3 / 64), 256, 0, stream>>>(
        rev_h, r_Wih, r_bih, gx3, NSEQ2, HDIM);

    // 7) Review-level GRU: 16 sequences x 16 steps
    gru_seq<2><<<NSEQ3 / 2, 768, 0, stream>>>(
        gx3, r_Whh, r_bhh, biz_h, T3);

    // 8) b_stars -> out[0..15]
    mlp_head<<<NSEQ3, 128, 0, stream>>>(
        biz_h, pfc_W1, pfc_b1, pfc_W2, pfc_b2, out);
}

// Round 3
// 706.139 us; speedup vs baseline: 3.9323x; 3.6459x over previous
//
#include <hip/hip_runtime.h>
#include <math.h>

// Sizes (fixed by the problem)
#define VOCAB 50000
#define EDIM  200
#define HDIM  256
#define G3    768      // 3*H
#define NSEQ1 4096     // B*R*S word sequences
#define T1    32       // W
#define NSEQ2 256      // B*R sentence sequences
#define T2    16       // S
#define NSEQ3 16       // B review sequences
#define T3    16       // R

using bf16x8 = __attribute__((ext_vector_type(8))) short;
using f32x4  = __attribute__((ext_vector_type(4))) float;

__device__ __forceinline__ float sigmoid_f(float x) {
    return 1.0f / (1.0f + __expf(-x));
}
__device__ __forceinline__ float tanh_f(float x) {
    return 1.0f - 2.0f / (__expf(2.0f * x) + 1.0f);
}
// f32 -> bf16 (RNE), bit-exact deterministic
__device__ __forceinline__ short f2b(float f) {
    unsigned u = __float_as_uint(f);
    unsigned r = (u + 0x7fffu + ((u >> 16) & 1u)) >> 16;
    return (short)r;
}

// ---------------------------------------------------------------------------
// Convert f32 [R][Kin] row-major -> bf16 [R][Kpad] with zero pad (k >= Kin).
// grid = R, block = 256.
// ---------------------------------------------------------------------------
__global__ void convert_pad(const float* __restrict__ src, short* __restrict__ dst,
                            int Kin, int Kpad) {
    const int r = blockIdx.x;
    for (int k = threadIdx.x; k < Kpad; k += blockDim.x)
        dst[(size_t)r * Kpad + k] = (k < Kin) ? f2b(src[(size_t)r * Kin + k]) : (short)0;
}

// ---------------------------------------------------------------------------
// C[M,768] = A[M,Keff] @ WB[768,KPAD]^T + bias  via bf16 MFMA, f32 out.
// KC = KPAD/32. A is f32 (AF32) or bf16 (row stride = Keff either way).
// Block 512 (8 waves): wave w owns M-tile w; 12 N-tiles (BN=192).
// A tile staged in LDS, 16B-cell XOR swizzle (cell ^= row&7) both sides.
// grid: (ceil(M/128), 4).
// ---------------------------------------------------------------------------
template <int KC, bool AF32>
__global__ __launch_bounds__(512) void gemm_mfma(
    const void* __restrict__ Av, const short* __restrict__ WB,
    const float* __restrict__ bias, float* __restrict__ C,
    int M, int Keff) {
    constexpr int KPAD  = KC * 32;
    constexpr int CELLS = KPAD / 8;          // 28 or 32 (row padded to 32 cells)
    __shared__ short As[128 * 256];          // 64 KB, row stride 256 shorts
    const int tid = threadIdx.x;
    const int m0 = blockIdx.x * 128;
    const int n0 = blockIdx.y * 192;

    // ---- stage A (f32->bf16 convert if needed), swizzled ----
    {
        const int row  = tid >> 2;           // 0..127
        const int c0   = (tid & 3) * 8;      // starting cell
        const int rowg = m0 + row;
        const int vcell = Keff >> 3;         // valid cells (200/8=25, 256/8=32)
        for (int i = 0; i < 8; i++) {
            const int c = c0 + i;
            if (c >= CELLS) break;
            bf16x8 v;
            if (rowg < M && c < vcell) {
                if constexpr (AF32) {
                    const float* ap = (const float*)Av + (size_t)rowg * Keff + c * 8;
                    const float4 x = *(const float4*)ap;
                    const float4 y = *(const float4*)(ap + 4);
                    v[0] = f2b(x.x); v[1] = f2b(x.y); v[2] = f2b(x.z); v[3] = f2b(x.w);
                    v[4] = f2b(y.x); v[5] = f2b(y.y); v[6] = f2b(y.z); v[7] = f2b(y.w);
                } else {
                    const short* ap = (const short*)Av + (size_t)rowg * Keff + c * 8;
                    v = *(const bf16x8*)ap;
                }
            } else {
                v = (bf16x8)(short)0;
            }
            *(bf16x8*)&As[row * 256 + ((c ^ (row & 7)) << 3)] = v;
        }
    }
    __syncthreads();

    // ---- MFMA ----
    const int w  = tid >> 6;                 // wave = M-tile
    const int l  = tid & 63;
    const int lr = l & 15, lg = l >> 4;

    bf16x8 af[KC];
    {
        const int row = (w << 4) + lr;
#pragma unroll
        for (int kc = 0; kc < KC; kc++) {
            const int cell = kc * 4 + lg;
            af[kc] = *(const bf16x8*)&As[row * 256 + ((cell ^ (row & 7)) << 3)];
        }
    }
    f32x4 acc[12];
#pragma unroll
    for (int nt = 0; nt < 12; nt++) acc[nt] = (f32x4){0.f, 0.f, 0.f, 0.f};
#pragma unroll
    for (int nt = 0; nt < 12; nt++) {
        const short* wb = WB + (size_t)(n0 + nt * 16 + lr) * KPAD + lg * 8;
#pragma unroll
        for (int kc = 0; kc < KC; kc++) {
            bf16x8 bf = *(const bf16x8*)(wb + kc * 32);
            acc[nt] = __builtin_amdgcn_mfma_f32_16x16x32_bf16(af[kc], bf, acc[nt], 0, 0, 0);
        }
    }
    // ---- epilogue: D layout col=lane&15, row=(lane>>4)*4+q (m89-verified) ----
#pragma unroll
    for (int nt = 0; nt < 12; nt++) {
        const int col = n0 + nt * 16 + lr;
        const float bv = bias[col];
#pragma unroll
        for (int q = 0; q < 4; q++) {
            const int row = m0 + (w << 4) + lg * 4 + q;
            if (row < M) C[(size_t)row * G3 + col] = acc[nt][q] + bv;
        }
    }
}

// ---------------------------------------------------------------------------
// MFMA GRU: block 512 (8 waves), TM=16 sequences/block, one M=16 tile.
// Wave w owns j-tile-triples tt in {2w, 2w+1}: N-tiles {tt, 16+tt, 32+tt}
// (r,z,n gates for cols j = tt*16 + lane&15) -> phase B fully in-register.
// h kept f32 in regs (exact elementwise recurrence); bf16 copy in swizzled
// LDS feeds the next step's A-fragments. Weights streamed bf16 from L2.
// gather mode (idx != null): gx rows = P[tok]; dense: gx[(n0+s)*T + t].
// ---------------------------------------------------------------------------
__global__ __launch_bounds__(512) void gru_mfma(
    const int* __restrict__ idx,
    const float* __restrict__ gxsrc,
    const short* __restrict__ WB,       // [768][256] bf16
    const float* __restrict__ bhh,
    float* __restrict__ hf32,           // optional [N][256]
    short* __restrict__ hb16,           // optional [N][256]
    int T) {
    __shared__ short hsB[16 * 256];     // 8 KB, swizzled bf16 h
    const int tid = threadIdx.x;
    const int n0 = blockIdx.x * 16;
    const int w  = tid >> 6, l = tid & 63;
    const int lr = l & 15, lg = l >> 4;
    const int tt0 = w * 2;

    for (int i = tid; i < 16 * 256; i += 512) hsB[i] = 0;

    float bR[2], bZ[2], bN[2];
#pragma unroll
    for (int ti = 0; ti < 2; ti++) {
        const int jj = (tt0 + ti) * 16 + lr;
        bR[ti] = bhh[jj]; bZ[ti] = bhh[256 + jj]; bN[ti] = bhh[512 + jj];
    }
    float hreg[2][4] = {};
    int toks[4];
    if (idx) {
#pragma unroll
        for (int q = 0; q < 4; q++) toks[q] = idx[(size_t)(n0 + lg * 4 + q) * T];
    }
    __syncthreads();

    for (int t = 0; t < T; t++) {
        // ---- gx prefetch (independent of h; hides L3 latency under MFMA) ----
        float gxv[2][4][3];
#pragma unroll
        for (int q = 0; q < 4; q++) {
            const size_t rowbase = idx ? (size_t)toks[q] * G3
                                       : ((size_t)(n0 + lg * 4 + q) * T + t) * G3;
#pragma unroll
            for (int ti = 0; ti < 2; ti++) {
                const int jj = (tt0 + ti) * 16 + lr;
                gxv[ti][q][0] = gxsrc[rowbase + jj];
                gxv[ti][q][1] = gxsrc[rowbase + 256 + jj];
                gxv[ti][q][2] = gxsrc[rowbase + 512 + jj];
            }
        }
        // ---- A-fragments: h bf16 from swizzled LDS ----
        bf16x8 af[8];
#pragma unroll
        for (int kc = 0; kc < 8; kc++) {
            const int cell = kc * 4 + lg;
            af[kc] = *(const bf16x8*)&hsB[lr * 256 + ((cell ^ (lr & 7)) << 3)];
        }
        __syncthreads();   // all waves have h in regs before anyone overwrites

        // ---- MFMA: 2 triples x 3 gates x 8 K-chunks = 48 ----
        f32x4 acc[2][3];
#pragma unroll
        for (int ti = 0; ti < 2; ti++)
#pragma unroll
            for (int g = 0; g < 3; g++) acc[ti][g] = (f32x4){0.f, 0.f, 0.f, 0.f};
#pragma unroll
        for (int ti = 0; ti < 2; ti++) {
#pragma unroll
            for (int g = 0; g < 3; g++) {
                const short* wb = WB + (size_t)(g * 256 + (tt0 + ti) * 16 + lr) * 256 + lg * 8;
#pragma unroll
                for (int kc = 0; kc < 8; kc++) {
                    bf16x8 bf = *(const bf16x8*)(wb + kc * 32);
                    acc[ti][g] = __builtin_amdgcn_mfma_f32_16x16x32_bf16(af[kc], bf, acc[ti][g], 0, 0, 0);
                }
            }
        }
        // ---- prefetch next tokens ----
        if (idx && t + 1 < T) {
#pragma unroll
            for (int q = 0; q < 4; q++) toks[q] = idx[(size_t)(n0 + lg * 4 + q) * T + t + 1];
        }
        // ---- phase B: in-register gates; D row=(lg*4+q), col=j ----
#pragma unroll
        for (int ti = 0; ti < 2; ti++) {
            const int jj = (tt0 + ti) * 16 + lr;
#pragma unroll
            for (int q = 0; q < 4; q++) {
                const float r = sigmoid_f(gxv[ti][q][0] + acc[ti][0][q] + bR[ti]);
                const float z = sigmoid_f(gxv[ti][q][1] + acc[ti][1][q] + bZ[ti]);
                const float n = tanh_f(gxv[ti][q][2] + r * (acc[ti][2][q] + bN[ti]));
                const float h = (1.f - z) * n + z * hreg[ti][q];
                hreg[ti][q] = h;
                const int s = lg * 4 + q;
                hsB[s * 256 + (((jj >> 3) ^ (s & 7)) << 3) + (jj & 7)] = f2b(h);
            }
        }
        __syncthreads();
    }
    // ---- epilogue ----
#pragma unroll
    for (int ti = 0; ti < 2; ti++) {
        const int jj = (tt0 + ti) * 16 + lr;
#pragma unroll
        for (int q = 0; q < 4; q++) {
            const int s = lg * 4 + q;
            const size_t o = (size_t)(n0 + s) * HDIM + jj;
            if (hf32) hf32[o] = hreg[ti][q];
            if (hb16) hb16[o] = f2b(hreg[ti][q]);
        }
    }
}

// ---------------------------------------------------------------------------
// MLP head: out[row] = selu(h[row]@W1^T + b1) @ W2^T + b2  (f32, tiny)
// ---------------------------------------------------------------------------
__global__ __launch_bounds__(128) void mlp_head(
    const float* __restrict__ hin, const float* __restrict__ W1,
    const float* __restrict__ b1, const float* __restrict__ W2,
    const float* __restrict__ b2, float* __restrict__ out) {
    const int row = blockIdx.x;
    const int gg = threadIdx.x;
    const float* h = hin + (size_t)row * HDIM;
    const float* wv1 = W1 + (size_t)gg * HDIM;
    float acc = 0.f;
#pragma unroll 4
    for (int k = 0; k < HDIM; k += 4) {
        const float4 hv = *(const float4*)&h[k];
        const float4 wv = *(const float4*)&wv1[k];
        acc += hv.x * wv.x; acc += hv.y * wv.y;
        acc += hv.z * wv.z; acc += hv.w * wv.w;
    }
    acc += b1[gg];
    const float alpha = 1.6732632423543772f;
    const float scale = 1.0507009873554805f;
    const float s = scale * (acc > 0.f ? acc : alpha * expm1f(acc));
    float v = s * W2[gg];

    __shared__ float red[128];
    red[gg] = v;
    __syncthreads();
    if (gg < 64) {
        float x = red[gg] + red[gg + 64];
#pragma unroll
        for (int off = 32; off; off >>= 1) x += __shfl_down(x, off);
        if (gg == 0) out[row] = x + b2[0];
    }
}

// ---------------------------------------------------------------------------
extern "C" void kernel_launch(void* const* d_in, const int* in_sizes, int n_in,
                              void* d_out, int out_size, void* d_ws, size_t ws_size,
                              hipStream_t stream) {
    const int*   idx    = (const int*)d_in[0];
    const float* emb    = (const float*)d_in[1];
    const float* w_Wih  = (const float*)d_in[2];
    const float* w_Whh  = (const float*)d_in[3];
    const float* w_bih  = (const float*)d_in[4];
    const float* w_bhh  = (const float*)d_in[5];
    const float* s_Wih  = (const float*)d_in[6];
    const float* s_Whh  = (const float*)d_in[7];
    const float* s_bih  = (const float*)d_in[8];
    const float* s_bhh  = (const float*)d_in[9];
    const float* r_Wih  = (const float*)d_in[10];
    const float* r_Whh  = (const float*)d_in[11];
    const float* r_bih  = (const float*)d_in[12];
    const float* r_bhh  = (const float*)d_in[13];
    const float* rfc_W1 = (const float*)d_in[14];
    const float* rfc_b1 = (const float*)d_in[15];
    const float* rfc_W2 = (const float*)d_in[16];
    const float* rfc_b2 = (const float*)d_in[17];
    const float* pfc_W1 = (const float*)d_in[18];
    const float* pfc_b1 = (const float*)d_in[19];
    const float* pfc_W2 = (const float*)d_in[20];
    const float* pfc_b2 = (const float*)d_in[21];

    float* out = (float*)d_out;      // [0..15] b_stars, [16..271] r_stars

    // ---- workspace layout ----
    float* fws = (float*)d_ws;
    float* P     = fws;                                    // 50000*768 f32
    float* gx2   = P     + (size_t)VOCAB * G3;             // 4096*768
    float* rev_h = gx2   + (size_t)NSEQ1 * G3;             // 256*256
    float* gx3   = rev_h + (size_t)NSEQ2 * HDIM;           // 256*768
    float* biz_h = gx3   + (size_t)NSEQ2 * G3;             // 16*256
    short* sws = (short*)(biz_h + (size_t)NSEQ3 * HDIM);
    short* WhhB_w = sws;                                   // 768*256 bf16
    short* WihB_w = WhhB_w + (size_t)G3 * HDIM;            // 768*224
    short* sWihB  = WihB_w + (size_t)G3 * 224;             // 768*256
    short* sWhhB  = sWihB  + (size_t)G3 * HDIM;
    short* rWihB  = sWhhB  + (size_t)G3 * HDIM;
    short* rWhhB  = rWihB  + (size_t)G3 * HDIM;
    short* sent_hB = rWhhB + (size_t)G3 * HDIM;            // 4096*256
    short* rev_hB  = sent_hB + (size_t)NSEQ1 * HDIM;       // 256*256

    // ---- weight conversions (bf16, padded where needed) ----
    convert_pad<<<G3, 256, 0, stream>>>(w_Whh, WhhB_w, HDIM, HDIM);
    convert_pad<<<G3, 256, 0, stream>>>(w_Wih, WihB_w, EDIM, 224);
    convert_pad<<<G3, 256, 0, stream>>>(s_Wih, sWihB, HDIM, HDIM);
    convert_pad<<<G3, 256, 0, stream>>>(s_Whh, sWhhB, HDIM, HDIM);
    convert_pad<<<G3, 256, 0, stream>>>(r_Wih, rWihB, HDIM, HDIM);
    convert_pad<<<G3, 256, 0, stream>>>(r_Whh, rWhhB, HDIM, HDIM);

    // 1) P = emb @ w_Wih^T + w_bih  [50000 x 768], Keff=200, KPAD=224
    gemm_mfma<7, true><<<dim3((VOCAB + 127) / 128, 4), 512, 0, stream>>>(
        emb, WihB_w, w_bih, P, VOCAB, EDIM);

    // 2) Word-level GRU (gather mode): 4096 seqs x 32 steps
    gru_mfma<<<NSEQ1 / 16, 512, 0, stream>>>(
        idx, P, WhhB_w, w_bhh, nullptr, sent_hB, T1);

    // 3) gx2 = sent_h @ s_Wih^T + s_bih  [4096 x 768], K=256 (bf16 A)
    gemm_mfma<8, false><<<dim3(NSEQ1 / 128, 4), 512, 0, stream>>>(
        sent_hB, sWihB, s_bih, gx2, NSEQ1, HDIM);

    // 4) Sentence-level GRU (dense): 256 seqs x 16 steps
    gru_mfma<<<NSEQ2 / 16, 512, 0, stream>>>(
        nullptr, gx2, sWhhB, s_bhh, rev_h, rev_hB, T2);

    // 5) r_stars -> out[16..271]
    mlp_head<<<NSEQ2, 128, 0, stream>>>(
        rev_h, rfc_W1, rfc_b1, rfc_W2, rfc_b2, out + 16);

    // 6) gx3 = rev_h @ r_Wih^T + r_bih  [256 x 768], K=256 (bf16 A)
    gemm_mfma<8, false><<<dim3(2, 4), 512, 0, stream>>>(
        rev_hB, rWihB, r_bih, gx3, NSEQ2, HDIM);

    // 7) Review-level GRU (dense): 16 seqs x 16 steps, single block
    gru_mfma<<<1, 512, 0, stream>>>(
        nullptr, gx3, rWhhB, r_bhh, biz_h, nullptr, T3);

    // 8) b_stars -> out[0..15]
    mlp_head<<<NSEQ3, 128, 0, stream>>>(
        biz_h, pfc_W1, pfc_b1, pfc_W2, pfc_b2, out);
}